// Round 18
// baseline (80.640 us; speedup 1.0000x reference)
//
#include <hip/hip_runtime.h>

typedef float v2f __attribute__((ext_vector_type(2)));
typedef float v4f __attribute__((ext_vector_type(4)));
typedef __fp16 h2 __attribute__((ext_vector_type(2)));
typedef __fp16 h4 __attribute__((ext_vector_type(4)));

#define B_ 64
#define T_ 2048
#define D_ 512
#define K_ 8
#define THREADS 256
#define TILE_R 32
#define XPITCH 520   // f16 pitch: 512 + 8 pad
#define LGP 9        // logits pitch (f32)
#define APITCH 12    // a-table pitch (f32)
#define SPITCH 36    // writeout scratch pitch (f32, 16B-aligned, 8-way max)
#define LOG2E 1.44269504088896340736f

__device__ __forceinline__ float dev_exp2(float v) { return __builtin_amdgcn_exp2f(v); }
__device__ __forceinline__ h2 pack2(float a, float b) { return __builtin_amdgcn_cvt_pkrtz(a, b); }

// Round 18: LDS-pipe diet. Seven k1 variants all land 71-75us; arithmetic
// says R11/R13 spend ~40us chip-wide in LDS instruction slots (m134:
// b128~12cyc) on top of the 38us HBM floor. This version:
//  - pass1 = MFMA (R13-verified layout), B-frags HOISTED to regs (W constant
//    across tiles) -> 16 A-frag ds_read_b64 per lane per tile
//  - pass2 runs from the STAGING REGISTERS (x never re-read from LDS; fp32)
//    thread owns rows {2i+half}, d-span (tid&127)*4; cross-half combine once
//  - stage writes packed h4 ds_write_b64
// LDS/lane/tile: 16 b64w + 16 b64r + 32 b128r(at broadcast) ~= 620cyc/wave
// -> ~10us chip-wide << HBM floor. LDS 48KB -> 3 blocks/CU; VGPR ~150.
template <int NCHUNK_T>
__global__ __launch_bounds__(THREADS) void k1_accum(
    const float* __restrict__ x, const float* __restrict__ attn_w,
    const float* __restrict__ attn_b, float* __restrict__ ax_part,
    float* __restrict__ asum_part) {
  constexpr int RPC = T_ / NCHUNK_T;
  constexpr int TILES = RPC / TILE_R;
  constexpr int KD = K_ * D_;

  const int blk = blockIdx.x;
  const int b = blk / NCHUNK_T;
  const int chunk = blk % NCHUNK_T;
  const int tid = threadIdx.x;
  const int wave = tid >> 6;
  const int lane = tid & 63;
  const int half = tid >> 7;        // 0: even rows, 1: odd rows
  const int dsp = (tid & 127) * 4;  // thread d-span

  __shared__ __align__(16) __fp16 xt[TILE_R * XPITCH];  // 33.3 KB (+ writeout scratch reuse)
  __shared__ __align__(16) __fp16 wt[K_ * XPITCH];      // 8.3 KB
  __shared__ float lg[4 * TILE_R * LGP];                // 4.6 KB
  __shared__ __align__(16) float at[TILE_R * APITCH];   // 1.5 KB
  __shared__ float bt[K_];

  // ---- stage W once (f16, pre-scaled by log2e; logits feed only softmax)
  {
    const int k = tid >> 5;
    const int d0 = (tid & 31) * 16;
    const float4* wp = (const float4*)(attn_w + k * D_ + d0);
    const float4 g0 = wp[0], g1 = wp[1], g2 = wp[2], g3 = wp[3];
    h2* wd = (h2*)(wt + k * XPITCH + d0);
    wd[0] = pack2(g0.x * LOG2E, g0.y * LOG2E);
    wd[1] = pack2(g0.z * LOG2E, g0.w * LOG2E);
    wd[2] = pack2(g1.x * LOG2E, g1.y * LOG2E);
    wd[3] = pack2(g1.z * LOG2E, g1.w * LOG2E);
    wd[4] = pack2(g2.x * LOG2E, g2.y * LOG2E);
    wd[5] = pack2(g2.z * LOG2E, g2.w * LOG2E);
    wd[6] = pack2(g3.x * LOG2E, g3.y * LOG2E);
    wd[7] = pack2(g3.z * LOG2E, g3.w * LOG2E);
  }
  if (tid < K_) bt[tid] = attn_b[tid] * LOG2E;

  // MFMA lane constants (layout verified on-silicon in round 13):
  //   A[m][k]: m=lane&15, k=(lane>>4)*4+i ; B[k][n]: n=lane&15, same k
  //   C[m][n]: n=lane&15, m=(lane>>4)*4+j
  const int m16 = lane & 15;
  const int kgrp = lane >> 4;
  const int koff = wave * 128 + kgrp * 4;  // wave owns a 128-d K-quarter
  const __fp16* arow0 = xt + m16 * XPITCH + koff;
  const __fp16* arow1 = xt + (16 + m16) * XPITCH + koff;
  const __fp16* brow = wt + (m16 < K_ ? m16 : (K_ - 1)) * XPITCH + koff;

  const float* xbase = x + ((size_t)b * T_ + (size_t)chunk * RPC) * (size_t)D_;

  float4 f0, f1, f2, f3, f4, f5, f6, f7, f8, f9, f10, f11, f12, f13, f14, f15;
#define LOADT(tt)                                                       \
  do {                                                                  \
    const float* s_ = xbase + (size_t)(tt) * TILE_R * D_ + tid * 4;     \
    f0 = *(const float4*)(s_ + 0 * 1024);                               \
    f1 = *(const float4*)(s_ + 1 * 1024);                               \
    f2 = *(const float4*)(s_ + 2 * 1024);                               \
    f3 = *(const float4*)(s_ + 3 * 1024);                               \
    f4 = *(const float4*)(s_ + 4 * 1024);                               \
    f5 = *(const float4*)(s_ + 5 * 1024);                               \
    f6 = *(const float4*)(s_ + 6 * 1024);                               \
    f7 = *(const float4*)(s_ + 7 * 1024);                               \
    f8 = *(const float4*)(s_ + 8 * 1024);                               \
    f9 = *(const float4*)(s_ + 9 * 1024);                               \
    f10 = *(const float4*)(s_ + 10 * 1024);                             \
    f11 = *(const float4*)(s_ + 11 * 1024);                             \
    f12 = *(const float4*)(s_ + 12 * 1024);                             \
    f13 = *(const float4*)(s_ + 13 * 1024);                             \
    f14 = *(const float4*)(s_ + 14 * 1024);                             \
    f15 = *(const float4*)(s_ + 15 * 1024);                             \
  } while (0)
  // thread's reg f_i holds row (2i+half), d [dsp, dsp+4)
#define WRT1(i, F)                                                      \
  do {                                                                  \
    const h2 lo_ = pack2(F.x, F.y), hi_ = pack2(F.z, F.w);              \
    h4 v_;                                                              \
    v_[0] = lo_[0]; v_[1] = lo_[1]; v_[2] = hi_[0]; v_[3] = hi_[1];     \
    *(h4*)(xt + (2 * (i) + half) * XPITCH + dsp) = v_;                  \
  } while (0)
#define WRITET()                                                        \
  do {                                                                  \
    WRT1(0, f0); WRT1(1, f1); WRT1(2, f2); WRT1(3, f3);                 \
    WRT1(4, f4); WRT1(5, f5); WRT1(6, f6); WRT1(7, f7);                 \
    WRT1(8, f8); WRT1(9, f9); WRT1(10, f10); WRT1(11, f11);             \
    WRT1(12, f12); WRT1(13, f13); WRT1(14, f14); WRT1(15, f15);         \
  } while (0)

  v2f acc2[K_][2];
#pragma unroll
  for (int k = 0; k < K_; ++k) {
    acc2[k][0] = (v2f){0.f, 0.f};
    acc2[k][1] = (v2f){0.f, 0.f};
  }
  float asum[K_];
#pragma unroll
  for (int k = 0; k < K_; ++k) asum[k] = 0.f;

  // prologue: issue tile0 loads early; sync for wt; hoist B-frags; write tile0
  LOADT(0);
  __syncthreads();  // wt/bt ready
  h4 bf[8];
#pragma unroll
  for (int s = 0; s < 8; ++s) bf[s] = *(const h4*)(brow + s * 16);
  WRITET();

  for (int t = 0; t < TILES; ++t) {
    __syncthreads();  // xt(t) ready

    // ---- pass1: logits = X(32x512)·W^T via MFMA; wave owns K-quarter
    {
      v4f c0 = {0.f, 0.f, 0.f, 0.f}, c1 = {0.f, 0.f, 0.f, 0.f};
#pragma unroll
      for (int s = 0; s < 8; ++s) {
        const h4 a0 = *(const h4*)(arow0 + s * 16);
        const h4 a1 = *(const h4*)(arow1 + s * 16);
        c0 = __builtin_amdgcn_mfma_f32_16x16x16f16(a0, bf[s], c0, 0, 0, 0);
        c1 = __builtin_amdgcn_mfma_f32_16x16x16f16(a1, bf[s], c1, 0, 0, 0);
      }
      if (m16 < K_) {
        const int base = (wave * TILE_R + kgrp * 4) * LGP + m16;
#pragma unroll
        for (int j = 0; j < 4; ++j) {
          lg[base + j * LGP] = c0[j];
          lg[base + (16 + j) * LGP] = c1[j];
        }
      }
    }
    __syncthreads();  // lg ready; all waves done reading xt

    // ---- softmax: lane-per-row (exp2 domain, no max-sub: logits ~N(0,1))
    if (wave == 0 && lane < TILE_R) {
      float e[K_];
      float tot = 0.f;
#pragma unroll
      for (int k = 0; k < K_; ++k) {
        const float l = ((lg[(0 * TILE_R + lane) * LGP + k] +
                          lg[(1 * TILE_R + lane) * LGP + k]) +
                         (lg[(2 * TILE_R + lane) * LGP + k] +
                          lg[(3 * TILE_R + lane) * LGP + k])) + bt[k];
        e[k] = dev_exp2(l);
        tot += e[k];
      }
      const float inv = __builtin_amdgcn_rcpf(tot);
      float4* ad = (float4*)(at + lane * APITCH);
      ad[0] = (float4){e[0] * inv, e[1] * inv, e[2] * inv, e[3] * inv};
      ad[1] = (float4){e[4] * inv, e[5] * inv, e[6] * inv, e[7] * inv};
#pragma unroll
      for (int k = 0; k < K_; ++k) asum[k] += e[k] * inv;
    }
    __syncthreads();  // at ready

    // ---- pass2: from staging registers (fp32 x), a broadcast from LDS
#define P2ROW(i, F)                                                          \
    do {                                                                     \
      const float* ar_ = at + (2 * (i) + half) * APITCH;                     \
      const float4 alo_ = *(const float4*)ar_;                               \
      const float4 ahi_ = *(const float4*)(ar_ + 4);                         \
      const v2f xl_ = {F.x, F.y}, xh_ = {F.z, F.w};                          \
      acc2[0][0] += (v2f){alo_.x, alo_.x} * xl_;                             \
      acc2[0][1] += (v2f){alo_.x, alo_.x} * xh_;                             \
      acc2[1][0] += (v2f){alo_.y, alo_.y} * xl_;                             \
      acc2[1][1] += (v2f){alo_.y, alo_.y} * xh_;                             \
      acc2[2][0] += (v2f){alo_.z, alo_.z} * xl_;                             \
      acc2[2][1] += (v2f){alo_.z, alo_.z} * xh_;                             \
      acc2[3][0] += (v2f){alo_.w, alo_.w} * xl_;                             \
      acc2[3][1] += (v2f){alo_.w, alo_.w} * xh_;                             \
      acc2[4][0] += (v2f){ahi_.x, ahi_.x} * xl_;                             \
      acc2[4][1] += (v2f){ahi_.x, ahi_.x} * xh_;                             \
      acc2[5][0] += (v2f){ahi_.y, ahi_.y} * xl_;                             \
      acc2[5][1] += (v2f){ahi_.y, ahi_.y} * xh_;                             \
      acc2[6][0] += (v2f){ahi_.z, ahi_.z} * xl_;                             \
      acc2[6][1] += (v2f){ahi_.z, ahi_.z} * xh_;                             \
      acc2[7][0] += (v2f){ahi_.w, ahi_.w} * xl_;                             \
      acc2[7][1] += (v2f){ahi_.w, ahi_.w} * xh_;                             \
    } while (0)
    P2ROW(0, f0); P2ROW(1, f1); P2ROW(2, f2); P2ROW(3, f3);
    P2ROW(4, f4); P2ROW(5, f5); P2ROW(6, f6); P2ROW(7, f7);
    P2ROW(8, f8); P2ROW(9, f9); P2ROW(10, f10); P2ROW(11, f11);
    P2ROW(12, f12); P2ROW(13, f13); P2ROW(14, f14); P2ROW(15, f15);
#undef P2ROW

    // stage next tile (regs free; xt safe: all waves passed the lg-sync)
    if (t + 1 < TILES) {
      LOADT(t + 1);
      WRITET();
    }
  }
#undef LOADT
#undef WRT1
#undef WRITET

  // ---- combine halves (even/odd rows) and write per-chunk partials
  __syncthreads();
  float* xf = (float*)xt;  // reuse xt as scratch: 128*SPITCH*4 = 18.4 KB
  if (half) {
    float* dst = xf + (tid & 127) * SPITCH;
#pragma unroll
    for (int k = 0; k < K_; ++k)
      *(float4*)(dst + k * 4) = (float4){acc2[k][0].x, acc2[k][0].y,
                                         acc2[k][1].x, acc2[k][1].y};
  }
  __syncthreads();
  if (!half) {
    const float* sp = xf + tid * SPITCH;
    float* op = ax_part + (size_t)blk * KD;
#pragma unroll
    for (int k = 0; k < K_; ++k) {
      const float4 o = *(const float4*)(sp + k * 4);
      *(float4*)(op + k * D_ + dsp) =
          (float4){acc2[k][0].x + o.x, acc2[k][0].y + o.y,
                   acc2[k][1].x + o.z, acc2[k][1].y + o.w};
    }
  }
  // asum: reduce across the 32 row-owning lanes of wave 0 (once per block)
  if (wave == 0 && lane < TILE_R) {
#pragma unroll
    for (int k = 0; k < K_; ++k) {
      float v = asum[k];
      v += __shfl_xor(v, 1);
      v += __shfl_xor(v, 2);
      v += __shfl_xor(v, 4);
      v += __shfl_xor(v, 8);
      v += __shfl_xor(v, 16);
      asum[k] = v;
    }
    if (lane == 0) {
      float* ap = asum_part + blk * K_;
#pragma unroll
      for (int k = 0; k < K_; ++k) ap[k] = asum[k];
    }
  }
}

// k2a: 4 blocks per batch -> reduce chunks, subtract asum*centers, partial sq
template <int NCHUNK_T>
__global__ __launch_bounds__(256) void k2a(
    const float* __restrict__ ax_part, const float* __restrict__ asum_part,
    const float* __restrict__ centers, float* __restrict__ pbuf,
    float* __restrict__ sqpart) {
  const int b = blockIdx.x >> 2;
  const int q = blockIdx.x & 3;
  const int tid = threadIdx.x;
  __shared__ float s_as[K_];
  __shared__ float s_sq[4];
  if (tid < K_) {
    float s = 0.f;
    for (int c = 0; c < NCHUNK_T; ++c) s += asum_part[(b * NCHUNK_T + c) * K_ + tid];
    s_as[tid] = s;
  }
  __syncthreads();
  const int idx = q * 1024 + tid * 4;
  float4 s = {0.f, 0.f, 0.f, 0.f};
  const float* base = ax_part + (size_t)b * NCHUNK_T * (K_ * D_) + idx;
  for (int c = 0; c < NCHUNK_T; ++c) {
    const float4 v = *(const float4*)(base + (size_t)c * (K_ * D_));
    s.x += v.x; s.y += v.y; s.z += v.z; s.w += v.w;
  }
  const int k = idx >> 9;
  const float a = s_as[k];
  const float4 cv = *(const float4*)(centers + idx);
  float4 p;
  p.x = s.x - a * cv.x; p.y = s.y - a * cv.y;
  p.z = s.z - a * cv.z; p.w = s.w - a * cv.w;
  *(float4*)(pbuf + (size_t)b * (K_ * D_) + idx) = p;
  float sq = p.x * p.x + p.y * p.y + p.z * p.z + p.w * p.w;
#pragma unroll
  for (int m = 32; m; m >>= 1) sq += __shfl_xor(sq, m);
  if ((tid & 63) == 0) s_sq[tid >> 6] = sq;
  __syncthreads();
  if (tid == 0) sqpart[blockIdx.x] = (s_sq[0] + s_sq[1]) + (s_sq[2] + s_sq[3]);
}

// k2b: normalize (pbuf is L2/L3-hot)
__global__ __launch_bounds__(1024) void k2b(const float* __restrict__ pbuf,
                                            const float* __restrict__ sqpart,
                                            float* __restrict__ out) {
  const int b = blockIdx.x;
  const float tot =
      (sqpart[b * 4] + sqpart[b * 4 + 1]) + (sqpart[b * 4 + 2] + sqpart[b * 4 + 3]);
  const float invn = 1.0f / fmaxf(__builtin_sqrtf(tot), 1e-12f);
  const int idx = threadIdx.x * 4;
  const float4 p = *(const float4*)(pbuf + (size_t)b * (K_ * D_) + idx);
  *(float4*)(out + (size_t)b * (K_ * D_) + idx) =
      (float4){p.x * invn, p.y * invn, p.z * invn, p.w * invn};
}

// legacy single-kernel finalize (smallest-workspace fallback)
template <int NCHUNK_T>
__global__ __launch_bounds__(1024) void k2_old(
    const float* __restrict__ ax_part, const float* __restrict__ asum_part,
    const float* __restrict__ centers, float* __restrict__ out) {
  const int b = blockIdx.x;
  const int tid = threadIdx.x;
  const int wave = tid >> 6;
  const int lane = tid & 63;
  __shared__ float s_asum[K_];
  __shared__ float s_sq[16];
  if (tid < K_) {
    float s = 0.f;
    for (int c = 0; c < NCHUNK_T; ++c) s += asum_part[(b * NCHUNK_T + c) * K_ + tid];
    s_asum[tid] = s;
  }
  __syncthreads();
  const int NPT = (K_ * D_) / 1024;
  float pooled[NPT];
  float sq = 0.f;
  const float* base = ax_part + (size_t)b * NCHUNK_T * (K_ * D_);
#pragma unroll
  for (int i = 0; i < NPT; ++i) {
    const int idx = tid + i * 1024;
    float v = 0.f;
    for (int c = 0; c < NCHUNK_T; ++c) v += base[(size_t)c * (K_ * D_) + idx];
    v -= s_asum[idx >> 9] * centers[idx];
    pooled[i] = v;
    sq = fmaf(v, v, sq);
  }
#pragma unroll
  for (int m = 32; m; m >>= 1) sq += __shfl_xor(sq, m);
  if (lane == 0) s_sq[wave] = sq;
  __syncthreads();
  float tot = 0.f;
#pragma unroll
  for (int wv = 0; wv < 16; ++wv) tot += s_sq[wv];
  const float invn = 1.0f / fmaxf(__builtin_sqrtf(tot), 1e-12f);
#pragma unroll
  for (int i = 0; i < NPT; ++i)
    out[(size_t)b * (K_ * D_) + tid + i * 1024] = pooled[i] * invn;
}

extern "C" void kernel_launch(void* const* d_in, const int* in_sizes, int n_in,
                              void* d_out, int out_size, void* d_ws, size_t ws_size,
                              hipStream_t stream) {
  (void)in_sizes; (void)n_in; (void)out_size;
  const float* x = (const float*)d_in[0];
  const float* centers = (const float*)d_in[1];
  const float* attn_w = (const float*)d_in[2];
  const float* attn_b = (const float*)d_in[3];
  float* out = (float*)d_out;

  const size_t KD = (size_t)K_ * D_;
  const size_t need16 = (size_t)B_ * 16 * KD * 4 + (size_t)B_ * 16 * K_ * 4 +
                        (size_t)B_ * KD * 4 + (size_t)B_ * 4 * 4;
  const size_t need8 = (size_t)B_ * 8 * KD * 4 + (size_t)B_ * 8 * K_ * 4 +
                       (size_t)B_ * KD * 4 + (size_t)B_ * 4 * 4;

  if (ws_size >= need16) {
    float* ax = (float*)d_ws;
    float* as = ax + (size_t)B_ * 16 * KD;
    float* pb = as + (size_t)B_ * 16 * K_;
    float* sp = pb + (size_t)B_ * KD;
    k1_accum<16><<<B_ * 16, THREADS, 0, stream>>>(x, attn_w, attn_b, ax, as);
    k2a<16><<<B_ * 4, 256, 0, stream>>>(ax, as, centers, pb, sp);
    k2b<<<B_, 1024, 0, stream>>>(pb, sp, out);
  } else if (ws_size >= need8) {
    float* ax = (float*)d_ws;
    float* as = ax + (size_t)B_ * 8 * KD;
    float* pb = as + (size_t)B_ * 8 * K_;
    float* sp = pb + (size_t)B_ * KD;
    k1_accum<8><<<B_ * 8, THREADS, 0, stream>>>(x, attn_w, attn_b, ax, as);
    k2a<8><<<B_ * 4, 256, 0, stream>>>(ax, as, centers, pb, sp);
    k2b<<<B_, 1024, 0, stream>>>(pb, sp, out);
  } else {
    float* ax = (float*)d_ws;
    float* as = ax + (size_t)B_ * 8 * KD;
    k1_accum<8><<<B_ * 8, THREADS, 0, stream>>>(x, attn_w, attn_b, ax, as);
    k2_old<8><<<B_, 1024, 0, stream>>>(ax, as, centers, out);
  }
}

// Round 19
// 75.991 us; speedup vs baseline: 1.0612x; 1.0612x over previous
//
#include <hip/hip_runtime.h>

typedef float v2f __attribute__((ext_vector_type(2)));
typedef __fp16 h2 __attribute__((ext_vector_type(2)));
typedef __fp16 h4 __attribute__((ext_vector_type(4)));
typedef __fp16 h8 __attribute__((ext_vector_type(8)));

#define B_ 64
#define T_ 2048
#define D_ 512
#define K_ 8
#define THREADS 256
#define TILE_R 32
#define XPITCH 520   // f16 pitch: 512 + 8 pad (row stride 1040B = 65*16 -> 16B-aligned)
#define LGPITCH 10
#define APITCH 12
#define LOG2E 1.44269504088896340736f

// Raw barrier discipline (T3/T4): __syncthreads() emits s_waitcnt vmcnt(0)
// before s_barrier (m97 barrier-drain) -- it killed every prior pipelining
// attempt (R12: drained at loop-top barrier; R18: loads issued after their
// consumer). Raw s_barrier + lgkmcnt(0) keeps global loads in flight across
// barriers; only LDS visibility is enforced.
#define LGKM0 asm volatile("s_waitcnt lgkmcnt(0)" ::: "memory")
#define BARRIER __builtin_amdgcn_s_barrier()
#define PIN __builtin_amdgcn_sched_barrier(0)

__device__ __forceinline__ float dev_exp2(float v) { return __builtin_amdgcn_exp2f(v); }
__device__ __forceinline__ h2 pack2(float a, float b) { return __builtin_amdgcn_cvt_pkrtz(a, b); }

__device__ __forceinline__ float fdot2(h2 a, h2 b, float c) {
#if __has_builtin(__builtin_amdgcn_fdot2)
  return __builtin_amdgcn_fdot2(a, b, c, false);
#else
  return c + (float)a[0] * (float)b[0] + (float)a[1] * (float)b[1];
#endif
}

// Round 19: R11 body + double-buffered xt + counted-vmcnt pipeline.
// Loads for tile t+2 issue at end of iter t; consumed by WRITET at end of
// iter t+1 (~1 full iteration of cover, never drained at barriers).
template <int NCHUNK_T>
__global__ __launch_bounds__(THREADS) void k1_accum(
    const float* __restrict__ x, const float* __restrict__ attn_w,
    const float* __restrict__ attn_b, float* __restrict__ ax_part,
    float* __restrict__ asum_part) {
  constexpr int RPC = T_ / NCHUNK_T;
  constexpr int TILES = RPC / TILE_R;  // >= 4

  const int blk = blockIdx.x;
  const int b = blk / NCHUNK_T;
  const int chunk = blk % NCHUNK_T;
  const int tid = threadIdx.x;
  const int wave = tid >> 6;
  const int lane = tid & 63;

  __shared__ __align__(16) __fp16 xt[2][TILE_R * XPITCH];  // 66.6 KB (dbuf)
  __shared__ __align__(16) __fp16 wt[K_ * XPITCH];         // 8.3 KB
  __shared__ float lg[TILE_R * LGPITCH];
  __shared__ __align__(16) float at[TILE_R * APITCH];

  // ---- stage W once (pre-scaled by log2e; logits feed only softmax)
  {
    const int k = tid >> 5;
    const int d0 = (tid & 31) * 16;
    const float4* wp = (const float4*)(attn_w + k * D_ + d0);
    const float4 g0 = wp[0], g1 = wp[1], g2 = wp[2], g3 = wp[3];
    h2* wd = (h2*)(wt + k * XPITCH + d0);
    wd[0] = pack2(g0.x * LOG2E, g0.y * LOG2E);
    wd[1] = pack2(g0.z * LOG2E, g0.w * LOG2E);
    wd[2] = pack2(g1.x * LOG2E, g1.y * LOG2E);
    wd[3] = pack2(g1.z * LOG2E, g1.w * LOG2E);
    wd[4] = pack2(g2.x * LOG2E, g2.y * LOG2E);
    wd[5] = pack2(g2.z * LOG2E, g2.w * LOG2E);
    wd[6] = pack2(g3.x * LOG2E, g3.y * LOG2E);
    wd[7] = pack2(g3.z * LOG2E, g3.w * LOG2E);
  }

  const int r1 = lane & 31;
  const int myk = wave * 2 + (lane >> 5);
  const float mybias = attn_b[myk] * LOG2E;
  const int d0p2 = wave * 128 + lane * 2;

  v2f acc[K_];
#pragma unroll
  for (int k = 0; k < K_; ++k) acc[k] = (v2f){0.f, 0.f};
  v2f asum01 = {0.f, 0.f}, asum23 = {0.f, 0.f}, asum45 = {0.f, 0.f}, asum67 = {0.f, 0.f};

  const float* xbase = x + ((size_t)b * T_ + (size_t)chunk * RPC) * (size_t)D_;
  const int t4 = tid << 2;

  float4 f0, f1, f2, f3, f4, f5, f6, f7, f8, f9, f10, f11, f12, f13, f14, f15;
#define LOADT(tt)                                                    \
  do {                                                               \
    const float* s_ = xbase + (size_t)(tt) * TILE_R * D_ + t4;       \
    f0 = *(const float4*)(s_ + 0 * 1024);                            \
    f1 = *(const float4*)(s_ + 1 * 1024);                            \
    f2 = *(const float4*)(s_ + 2 * 1024);                            \
    f3 = *(const float4*)(s_ + 3 * 1024);                            \
    f4 = *(const float4*)(s_ + 4 * 1024);                            \
    f5 = *(const float4*)(s_ + 5 * 1024);                            \
    f6 = *(const float4*)(s_ + 6 * 1024);                            \
    f7 = *(const float4*)(s_ + 7 * 1024);                            \
    f8 = *(const float4*)(s_ + 8 * 1024);                            \
    f9 = *(const float4*)(s_ + 9 * 1024);                            \
    f10 = *(const float4*)(s_ + 10 * 1024);                          \
    f11 = *(const float4*)(s_ + 11 * 1024);                          \
    f12 = *(const float4*)(s_ + 12 * 1024);                          \
    f13 = *(const float4*)(s_ + 13 * 1024);                          \
    f14 = *(const float4*)(s_ + 14 * 1024);                          \
    f15 = *(const float4*)(s_ + 15 * 1024);                          \
  } while (0)
#define WRT1(BUF, i, F)                                              \
  do {                                                               \
    const int g_ = (i)*1024 + t4;                                    \
    const h2 lo_ = pack2(F.x, F.y), hi_ = pack2(F.z, F.w);           \
    h4 v_;                                                           \
    v_[0] = lo_[0]; v_[1] = lo_[1]; v_[2] = hi_[0]; v_[3] = hi_[1];  \
    *(h4*)(&(BUF)[(g_ >> 9) * XPITCH + (g_ & 511)]) = v_;            \
  } while (0)
#define WRITET(BUF)                                                  \
  do {                                                               \
    WRT1(BUF, 0, f0); WRT1(BUF, 1, f1); WRT1(BUF, 2, f2);            \
    WRT1(BUF, 3, f3); WRT1(BUF, 4, f4); WRT1(BUF, 5, f5);            \
    WRT1(BUF, 6, f6); WRT1(BUF, 7, f7); WRT1(BUF, 8, f8);            \
    WRT1(BUF, 9, f9); WRT1(BUF, 10, f10); WRT1(BUF, 11, f11);        \
    WRT1(BUF, 12, f12); WRT1(BUF, 13, f13); WRT1(BUF, 14, f14);      \
    WRT1(BUF, 15, f15);                                              \
  } while (0)

  // prologue: tile0 staged; tile1 loads in flight
  LOADT(0);
  WRITET(xt[0]);
  LOADT(1);
  PIN;          // pin tile1 issue point (don't let hipcc sink it)
  LGKM0;
  BARRIER;      // xt[0] + wt visible; tile1 loads STILL IN FLIGHT

#pragma unroll
  for (int t = 0; t < TILES; ++t) {
    const int cur = t & 1;

    // ---- pass1: full 512-deep dot per (row, k) lane; 4 indep chains
    {
      float s0 = 0.f, s1 = 0.f, s2 = 0.f, s3 = 0.f;
      const h8* xr = (const h8*)(&xt[cur][r1 * XPITCH]);
      const h8* wr = (const h8*)(wt + myk * XPITCH);
#pragma unroll 8
      for (int c = 0; c < 64; ++c) {
        const h8 xv = xr[c];
        const h8 wv = wr[c];
        s0 = fdot2((h2){xv[0], xv[1]}, (h2){wv[0], wv[1]}, s0);
        s1 = fdot2((h2){xv[2], xv[3]}, (h2){wv[2], wv[3]}, s1);
        s2 = fdot2((h2){xv[4], xv[5]}, (h2){wv[4], wv[5]}, s2);
        s3 = fdot2((h2){xv[6], xv[7]}, (h2){wv[6], wv[7]}, s3);
      }
      lg[r1 * LGPITCH + myk] = (s0 + s1) + (s2 + s3) + mybias;
    }
    LGKM0;
    BARRIER;  // lg visible

    // ---- softmax: lane-per-row, lane-local (exp2 domain, no max-sub:
    //      logits ~ N(0,1), fp32-safe; ratio identical)
    if (wave == 0 && lane < 32) {
      const float* lr = lg + lane * LGPITCH;
      float e0 = dev_exp2(lr[0]), e1 = dev_exp2(lr[1]);
      float e2 = dev_exp2(lr[2]), e3 = dev_exp2(lr[3]);
      float e4 = dev_exp2(lr[4]), e5 = dev_exp2(lr[5]);
      float e6 = dev_exp2(lr[6]), e7 = dev_exp2(lr[7]);
      const float tot = ((e0 + e1) + (e2 + e3)) + ((e4 + e5) + (e6 + e7));
      const float inv = __builtin_amdgcn_rcpf(tot);
      float4* ad = (float4*)(at + lane * APITCH);
      ad[0] = (float4){e0 * inv, e1 * inv, e2 * inv, e3 * inv};
      ad[1] = (float4){e4 * inv, e5 * inv, e6 * inv, e7 * inv};
    }
    LGKM0;
    BARRIER;  // at visible

    // ---- pass2: acc[k] += a[r][k] * x[r][d-pair]; a reads broadcast
#pragma unroll 4
    for (int rr = 0; rr < TILE_R; ++rr) {
      const float4 alo = *(const float4*)(at + rr * APITCH);
      const float4 ahi = *(const float4*)(at + rr * APITCH + 4);
      const h2 xp = *(const h2*)(&xt[cur][rr * XPITCH + d0p2]);
      const v2f xv = {(float)xp[0], (float)xp[1]};
      acc[0] += (v2f){alo.x, alo.x} * xv;
      acc[1] += (v2f){alo.y, alo.y} * xv;
      acc[2] += (v2f){alo.z, alo.z} * xv;
      acc[3] += (v2f){alo.w, alo.w} * xv;
      acc[4] += (v2f){ahi.x, ahi.x} * xv;
      acc[5] += (v2f){ahi.y, ahi.y} * xv;
      acc[6] += (v2f){ahi.z, ahi.z} * xv;
      acc[7] += (v2f){ahi.w, ahi.w} * xv;
      if (wave == 0) {
        asum01 += (v2f){alo.x, alo.y};
        asum23 += (v2f){alo.z, alo.w};
        asum45 += (v2f){ahi.x, ahi.y};
        asum67 += (v2f){ahi.z, ahi.w};
      }
    }

    // ---- drain tile t+1 loads into the other buffer; issue tile t+2
    if (t + 1 < TILES) {
      WRITET(xt[cur ^ 1]);  // counted vmcnt wait: loads issued 1 full iter ago
      if (t + 2 < TILES) {
        LOADT(t + 2);
        PIN;  // pin issue point at end of iter t
      }
    }
    LGKM0;
    BARRIER;  // xt[cur^1] visible for next iter; all waves synced
  }
#undef LOADT
#undef WRT1
#undef WRITET

  float* outp = ax_part + (size_t)blk * (K_ * D_);
#pragma unroll
  for (int k = 0; k < K_; ++k) *(v2f*)(outp + k * D_ + d0p2) = acc[k];
  if (tid == 0) {
    float* ap = asum_part + blk * K_;
    ap[0] = asum01.x; ap[1] = asum01.y; ap[2] = asum23.x; ap[3] = asum23.y;
    ap[4] = asum45.x; ap[5] = asum45.y; ap[6] = asum67.x; ap[7] = asum67.y;
  }
}

// k2a: 4 blocks per batch -> reduce chunks, subtract asum*centers, partial sq
template <int NCHUNK_T>
__global__ __launch_bounds__(256) void k2a(
    const float* __restrict__ ax_part, const float* __restrict__ asum_part,
    const float* __restrict__ centers, float* __restrict__ pbuf,
    float* __restrict__ sqpart) {
  const int b = blockIdx.x >> 2;
  const int q = blockIdx.x & 3;
  const int tid = threadIdx.x;
  __shared__ float s_as[K_];
  __shared__ float s_sq[4];
  if (tid < K_) {
    float s = 0.f;
    for (int c = 0; c < NCHUNK_T; ++c) s += asum_part[(b * NCHUNK_T + c) * K_ + tid];
    s_as[tid] = s;
  }
  __syncthreads();
  const int idx = q * 1024 + tid * 4;
  float4 s = {0.f, 0.f, 0.f, 0.f};
  const float* base = ax_part + (size_t)b * NCHUNK_T * (K_ * D_) + idx;
  for (int c = 0; c < NCHUNK_T; ++c) {
    const float4 v = *(const float4*)(base + (size_t)c * (K_ * D_));
    s.x += v.x; s.y += v.y; s.z += v.z; s.w += v.w;
  }
  const int k = idx >> 9;
  const float a = s_as[k];
  const float4 cv = *(const float4*)(centers + idx);
  float4 p;
  p.x = s.x - a * cv.x; p.y = s.y - a * cv.y;
  p.z = s.z - a * cv.z; p.w = s.w - a * cv.w;
  *(float4*)(pbuf + (size_t)b * (K_ * D_) + idx) = p;
  float sq = p.x * p.x + p.y * p.y + p.z * p.z + p.w * p.w;
#pragma unroll
  for (int m = 32; m; m >>= 1) sq += __shfl_xor(sq, m);
  if ((tid & 63) == 0) s_sq[tid >> 6] = sq;
  __syncthreads();
  if (tid == 0) sqpart[blockIdx.x] = (s_sq[0] + s_sq[1]) + (s_sq[2] + s_sq[3]);
}

// k2b: normalize (pbuf is L2/L3-hot)
__global__ __launch_bounds__(1024) void k2b(const float* __restrict__ pbuf,
                                            const float* __restrict__ sqpart,
                                            float* __restrict__ out) {
  const int b = blockIdx.x;
  const float tot =
      (sqpart[b * 4] + sqpart[b * 4 + 1]) + (sqpart[b * 4 + 2] + sqpart[b * 4 + 3]);
  const float invn = 1.0f / fmaxf(__builtin_sqrtf(tot), 1e-12f);
  const int idx = threadIdx.x * 4;
  const float4 p = *(const float4*)(pbuf + (size_t)b * (K_ * D_) + idx);
  *(float4*)(out + (size_t)b * (K_ * D_) + idx) =
      (float4){p.x * invn, p.y * invn, p.z * invn, p.w * invn};
}

// legacy single-kernel finalize (smallest-workspace fallback)
template <int NCHUNK_T>
__global__ __launch_bounds__(1024) void k2_old(
    const float* __restrict__ ax_part, const float* __restrict__ asum_part,
    const float* __restrict__ centers, float* __restrict__ out) {
  const int b = blockIdx.x;
  const int tid = threadIdx.x;
  const int wave = tid >> 6;
  const int lane = tid & 63;
  __shared__ float s_asum[K_];
  __shared__ float s_sq[16];
  if (tid < K_) {
    float s = 0.f;
    for (int c = 0; c < NCHUNK_T; ++c) s += asum_part[(b * NCHUNK_T + c) * K_ + tid];
    s_asum[tid] = s;
  }
  __syncthreads();
  const int NPT = (K_ * D_) / 1024;
  float pooled[NPT];
  float sq = 0.f;
  const float* base = ax_part + (size_t)b * NCHUNK_T * (K_ * D_);
#pragma unroll
  for (int i = 0; i < NPT; ++i) {
    const int idx = tid + i * 1024;
    float v = 0.f;
    for (int c = 0; c < NCHUNK_T; ++c) v += base[(size_t)c * (K_ * D_) + idx];
    v -= s_asum[idx >> 9] * centers[idx];
    pooled[i] = v;
    sq = fmaf(v, v, sq);
  }
#pragma unroll
  for (int m = 32; m; m >>= 1) sq += __shfl_xor(sq, m);
  if (lane == 0) s_sq[wave] = sq;
  __syncthreads();
  float tot = 0.f;
#pragma unroll
  for (int wv = 0; wv < 16; ++wv) tot += s_sq[wv];
  const float invn = 1.0f / fmaxf(__builtin_sqrtf(tot), 1e-12f);
#pragma unroll
  for (int i = 0; i < NPT; ++i)
    out[(size_t)b * (K_ * D_) + tid + i * 1024] = pooled[i] * invn;
}

extern "C" void kernel_launch(void* const* d_in, const int* in_sizes, int n_in,
                              void* d_out, int out_size, void* d_ws, size_t ws_size,
                              hipStream_t stream) {
  (void)in_sizes; (void)n_in; (void)out_size;
  const float* x = (const float*)d_in[0];
  const float* centers = (const float*)d_in[1];
  const float* attn_w = (const float*)d_in[2];
  const float* attn_b = (const float*)d_in[3];
  float* out = (float*)d_out;

  const size_t KD = (size_t)K_ * D_;
  const size_t need16 = (size_t)B_ * 16 * KD * 4 + (size_t)B_ * 16 * K_ * 4 +
                        (size_t)B_ * KD * 4 + (size_t)B_ * 4 * 4;
  const size_t need8 = (size_t)B_ * 8 * KD * 4 + (size_t)B_ * 8 * K_ * 4 +
                       (size_t)B_ * KD * 4 + (size_t)B_ * 4 * 4;

  if (ws_size >= need16) {
    float* ax = (float*)d_ws;
    float* as = ax + (size_t)B_ * 16 * KD;
    float* pb = as + (size_t)B_ * 16 * K_;
    float* sp = pb + (size_t)B_ * KD;
    k1_accum<16><<<B_ * 16, THREADS, 0, stream>>>(x, attn_w, attn_b, ax, as);
    k2a<16><<<B_ * 4, 256, 0, stream>>>(ax, as, centers, pb, sp);
    k2b<<<B_, 1024, 0, stream>>>(pb, sp, out);
  } else if (ws_size >= need8) {
    float* ax = (float*)d_ws;
    float* as = ax + (size_t)B_ * 8 * KD;
    float* pb = as + (size_t)B_ * 8 * K_;
    float* sp = pb + (size_t)B_ * KD;
    k1_accum<8><<<B_ * 8, THREADS, 0, stream>>>(x, attn_w, attn_b, ax, as);
    k2a<8><<<B_ * 4, 256, 0, stream>>>(ax, as, centers, pb, sp);
    k2b<<<B_, 1024, 0, stream>>>(pb, sp, out);
  } else {
    float* ax = (float*)d_ws;
    float* as = ax + (size_t)B_ * 8 * KD;
    k1_accum<8><<<B_ * 8, THREADS, 0, stream>>>(x, attn_w, attn_b, ax, as);
    k2_old<8><<<B_, 1024, 0, stream>>>(ax, as, centers, out);
  }
}

// Round 20
// 61.511 us; speedup vs baseline: 1.3110x; 1.2354x over previous
//
#include <hip/hip_runtime.h>

typedef float v2f __attribute__((ext_vector_type(2)));
typedef float v4f __attribute__((ext_vector_type(4)));
typedef __fp16 h2 __attribute__((ext_vector_type(2)));
typedef __fp16 h4 __attribute__((ext_vector_type(4)));

#define B_ 64
#define T_ 2048
#define D_ 512
#define K_ 8
#define THREADS 256
#define TILE_R 32
#define XPITCH 520   // f16 pitch: 512 + 8 pad
#define LGP 9        // logits pitch (f32)
#define APITCH 12    // a-table pitch (f32)
#define LOG2E 1.44269504088896340736f

// Raw barrier discipline (T3/T4): __syncthreads() drains vmcnt(0) before
// s_barrier -- keeps prefetch loads in flight across barriers instead.
#define LGKM0 asm volatile("s_waitcnt lgkmcnt(0)" ::: "memory")
#define BARRIER __builtin_amdgcn_s_barrier()
#define PIN __builtin_amdgcn_sched_barrier(0)

__device__ __forceinline__ float dev_exp2(float v) { return __builtin_amdgcn_exp2f(v); }
__device__ __forceinline__ h2 pack2(float a, float b) { return __builtin_amdgcn_cvt_pkrtz(a, b); }

// Round 20: joint-pipe fix. Cost model from 9 variants: R11's 70us == LDS
// pipe (2600cyc/wave/tile x 16 waves/CU x 4 tiles ~= 69us); every variant
// that cut LDS broke latency cover (R18) or kept the fdot2 pass1 (R19).
// This kernel: MFMA pass1 (16 ds_read_b64/lane/tile, B-frags hoisted once)
// + R11's proven pass2/softmax/writeout + R19's covered counted-vmcnt
// pipeline (loads for t+2 at end of iter t, raw barriers, never drained).
// LDS ~1150cyc/wave/tile -> ~23us chip-wide < 37us HBM floor.
// LDS 48KB -> 3 blocks/CU.
template <int NCHUNK_T>
__global__ __launch_bounds__(THREADS) void k1_accum(
    const float* __restrict__ x, const float* __restrict__ attn_w,
    const float* __restrict__ attn_b, float* __restrict__ ax_part,
    float* __restrict__ asum_part) {
  constexpr int RPC = T_ / NCHUNK_T;
  constexpr int TILES = RPC / TILE_R;  // 4 (NCHUNK=16) or 8 (NCHUNK=8)

  const int blk = blockIdx.x;
  const int b = blk / NCHUNK_T;
  const int chunk = blk % NCHUNK_T;
  const int tid = threadIdx.x;
  const int wave = tid >> 6;
  const int lane = tid & 63;

  __shared__ __align__(16) __fp16 xt[TILE_R * XPITCH];  // 33.3 KB (single buf)
  __shared__ __align__(16) __fp16 wt[K_ * XPITCH];      // 8.3 KB
  __shared__ float lg[4 * TILE_R * LGP];                // 4.6 KB (per-wave C partials)
  __shared__ __align__(16) float at[TILE_R * APITCH];   // 1.5 KB
  __shared__ float bt[K_];

  // ---- stage W once (f16, pre-scaled by log2e; logits feed only softmax)
  {
    const int k = tid >> 5;
    const int d0 = (tid & 31) * 16;
    const float4* wp = (const float4*)(attn_w + k * D_ + d0);
    const float4 g0 = wp[0], g1 = wp[1], g2 = wp[2], g3 = wp[3];
    h2* wd = (h2*)(wt + k * XPITCH + d0);
    wd[0] = pack2(g0.x * LOG2E, g0.y * LOG2E);
    wd[1] = pack2(g0.z * LOG2E, g0.w * LOG2E);
    wd[2] = pack2(g1.x * LOG2E, g1.y * LOG2E);
    wd[3] = pack2(g1.z * LOG2E, g1.w * LOG2E);
    wd[4] = pack2(g2.x * LOG2E, g2.y * LOG2E);
    wd[5] = pack2(g2.z * LOG2E, g2.w * LOG2E);
    wd[6] = pack2(g3.x * LOG2E, g3.y * LOG2E);
    wd[7] = pack2(g3.z * LOG2E, g3.w * LOG2E);
  }
  if (tid < K_) bt[tid] = attn_b[tid] * LOG2E;

  // MFMA lane constants (layout verified on-silicon R13/R18):
  //   A[m][k]: m=lane&15, k=(lane>>4)*4+i ; B[k][n]: n=lane&15, same k
  //   C[m][n]: n=lane&15, m=(lane>>4)*4+j
  const int m16 = lane & 15;
  const int kgrp = lane >> 4;
  const int koff = wave * 128 + kgrp * 4;  // wave owns a 128-d K-quarter
  const __fp16* arow0 = xt + m16 * XPITCH + koff;
  const __fp16* arow1 = xt + (16 + m16) * XPITCH + koff;
  const __fp16* brow = wt + (m16 < K_ ? m16 : (K_ - 1)) * XPITCH + koff;

  const int d0p2 = wave * 128 + lane * 2;  // pass2 d-pair ownership

  v2f acc[K_];
#pragma unroll
  for (int k = 0; k < K_; ++k) acc[k] = (v2f){0.f, 0.f};
  float asum[K_];
#pragma unroll
  for (int k = 0; k < K_; ++k) asum[k] = 0.f;

  const float* xbase = x + ((size_t)b * T_ + (size_t)chunk * RPC) * (size_t)D_;
  const int t4 = tid << 2;

  float4 f0, f1, f2, f3, f4, f5, f6, f7, f8, f9, f10, f11, f12, f13, f14, f15;
#define LOADT(tt)                                                    \
  do {                                                               \
    const float* s_ = xbase + (size_t)(tt) * TILE_R * D_ + t4;       \
    f0 = *(const float4*)(s_ + 0 * 1024);                            \
    f1 = *(const float4*)(s_ + 1 * 1024);                            \
    f2 = *(const float4*)(s_ + 2 * 1024);                            \
    f3 = *(const float4*)(s_ + 3 * 1024);                            \
    f4 = *(const float4*)(s_ + 4 * 1024);                            \
    f5 = *(const float4*)(s_ + 5 * 1024);                            \
    f6 = *(const float4*)(s_ + 6 * 1024);                            \
    f7 = *(const float4*)(s_ + 7 * 1024);                            \
    f8 = *(const float4*)(s_ + 8 * 1024);                            \
    f9 = *(const float4*)(s_ + 9 * 1024);                            \
    f10 = *(const float4*)(s_ + 10 * 1024);                          \
    f11 = *(const float4*)(s_ + 11 * 1024);                          \
    f12 = *(const float4*)(s_ + 12 * 1024);                          \
    f13 = *(const float4*)(s_ + 13 * 1024);                          \
    f14 = *(const float4*)(s_ + 14 * 1024);                          \
    f15 = *(const float4*)(s_ + 15 * 1024);                          \
  } while (0)
#define WRT1(i, F)                                                   \
  do {                                                               \
    const int g_ = (i)*1024 + t4;                                    \
    const h2 lo_ = pack2(F.x, F.y), hi_ = pack2(F.z, F.w);           \
    h4 v_;                                                           \
    v_[0] = lo_[0]; v_[1] = lo_[1]; v_[2] = hi_[0]; v_[3] = hi_[1];  \
    *(h4*)(xt + (g_ >> 9) * XPITCH + (g_ & 511)) = v_;               \
  } while (0)
#define WRITET()                                                     \
  do {                                                               \
    WRT1(0, f0); WRT1(1, f1); WRT1(2, f2); WRT1(3, f3);              \
    WRT1(4, f4); WRT1(5, f5); WRT1(6, f6); WRT1(7, f7);              \
    WRT1(8, f8); WRT1(9, f9); WRT1(10, f10); WRT1(11, f11);          \
    WRT1(12, f12); WRT1(13, f13); WRT1(14, f14); WRT1(15, f15);      \
  } while (0)

  // prologue: stage tile0; hoist B-frags; issue tile1 (stays in flight)
  LOADT(0);
  WRITET();
  LGKM0;
  BARRIER;  // xt(0) + wt visible
  h4 bf[8];
#pragma unroll
  for (int s = 0; s < 8; ++s) bf[s] = *(const h4*)(brow + s * 16);
  LOADT(1);
  PIN;  // pin tile1 issue point; loads cross barriers un-drained

#pragma unroll
  for (int t = 0; t < TILES; ++t) {
    // ---- pass1: logits = X·W^T via MFMA (A from xt, B from regs)
    {
      v4f c0 = {0.f, 0.f, 0.f, 0.f}, c1 = {0.f, 0.f, 0.f, 0.f};
#pragma unroll
      for (int s = 0; s < 8; ++s) {
        const h4 a0 = *(const h4*)(arow0 + s * 16);
        const h4 a1 = *(const h4*)(arow1 + s * 16);
        c0 = __builtin_amdgcn_mfma_f32_16x16x16f16(a0, bf[s], c0, 0, 0, 0);
        c1 = __builtin_amdgcn_mfma_f32_16x16x16f16(a1, bf[s], c1, 0, 0, 0);
      }
      if (m16 < K_) {
        const int base = (wave * TILE_R + kgrp * 4) * LGP + m16;
#pragma unroll
        for (int j = 0; j < 4; ++j) {
          lg[base + j * LGP] = c0[j];
          lg[base + (16 + j) * LGP] = c1[j];
        }
      }
    }
    LGKM0;
    BARRIER;  // lg visible

    // ---- softmax: lane-per-row (exp2 domain, no max-sub: logits ~N(0,1),
    //      fp32-safe; ratio identical). asum accumulated per owning lane.
    if (wave == 0 && lane < TILE_R) {
      float e[K_];
      float tot = 0.f;
#pragma unroll
      for (int k = 0; k < K_; ++k) {
        const float l = ((lg[(0 * TILE_R + lane) * LGP + k] +
                          lg[(1 * TILE_R + lane) * LGP + k]) +
                         (lg[(2 * TILE_R + lane) * LGP + k] +
                          lg[(3 * TILE_R + lane) * LGP + k])) + bt[k];
        e[k] = dev_exp2(l);
        tot += e[k];
      }
      const float inv = __builtin_amdgcn_rcpf(tot);
      float4* ad = (float4*)(at + lane * APITCH);
      ad[0] = (float4){e[0] * inv, e[1] * inv, e[2] * inv, e[3] * inv};
      ad[1] = (float4){e[4] * inv, e[5] * inv, e[6] * inv, e[7] * inv};
#pragma unroll
      for (int k = 0; k < K_; ++k) asum[k] += e[k] * inv;
    }
    LGKM0;
    BARRIER;  // at visible

    // ---- pass2: acc[k] += a[r][k] * x[r][d-pair]; a broadcast, x b32
#pragma unroll 4
    for (int rr = 0; rr < TILE_R; ++rr) {
      const float4 alo = *(const float4*)(at + rr * APITCH);
      const float4 ahi = *(const float4*)(at + rr * APITCH + 4);
      const h2 xp = *(const h2*)(xt + rr * XPITCH + d0p2);
      const v2f xv = {(float)xp[0], (float)xp[1]};
      acc[0] += (v2f){alo.x, alo.x} * xv;
      acc[1] += (v2f){alo.y, alo.y} * xv;
      acc[2] += (v2f){alo.z, alo.z} * xv;
      acc[3] += (v2f){alo.w, alo.w} * xv;
      acc[4] += (v2f){ahi.x, ahi.x} * xv;
      acc[5] += (v2f){ahi.y, ahi.y} * xv;
      acc[6] += (v2f){ahi.z, ahi.z} * xv;
      acc[7] += (v2f){ahi.w, ahi.w} * xv;
    }
    LGKM0;
    BARRIER;  // all waves done reading xt(t)

    // ---- drain tile t+1 into xt (loads issued a full iter ago: covered);
    //      issue tile t+2 (covered by next iter's pass1..pass2)
    if (t + 1 < TILES) {
      WRITET();
      if (t + 2 < TILES) {
        LOADT(t + 2);
        PIN;
      }
      LGKM0;
      BARRIER;  // xt(t+1) visible
    }
  }
#undef LOADT
#undef WRT1
#undef WRITET

  // ---- write per-chunk partials
  float* outp = ax_part + (size_t)blk * (K_ * D_);
#pragma unroll
  for (int k = 0; k < K_; ++k) *(v2f*)(outp + k * D_ + d0p2) = acc[k];
  // asum: reduce across the 32 row-owning lanes of wave 0
  if (wave == 0 && lane < TILE_R) {
#pragma unroll
    for (int k = 0; k < K_; ++k) {
      float v = asum[k];
      v += __shfl_xor(v, 1);
      v += __shfl_xor(v, 2);
      v += __shfl_xor(v, 4);
      v += __shfl_xor(v, 8);
      v += __shfl_xor(v, 16);
      asum[k] = v;
    }
    if (lane == 0) {
      float* ap = asum_part + blk * K_;
#pragma unroll
      for (int k = 0; k < K_; ++k) ap[k] = asum[k];
    }
  }
}

// k2a: 4 blocks per batch -> reduce chunks, subtract asum*centers, partial sq
template <int NCHUNK_T>
__global__ __launch_bounds__(256) void k2a(
    const float* __restrict__ ax_part, const float* __restrict__ asum_part,
    const float* __restrict__ centers, float* __restrict__ pbuf,
    float* __restrict__ sqpart) {
  const int b = blockIdx.x >> 2;
  const int q = blockIdx.x & 3;
  const int tid = threadIdx.x;
  __shared__ float s_as[K_];
  __shared__ float s_sq[4];
  if (tid < K_) {
    float s = 0.f;
    for (int c = 0; c < NCHUNK_T; ++c) s += asum_part[(b * NCHUNK_T + c) * K_ + tid];
    s_as[tid] = s;
  }
  __syncthreads();
  const int idx = q * 1024 + tid * 4;
  float4 s = {0.f, 0.f, 0.f, 0.f};
  const float* base = ax_part + (size_t)b * NCHUNK_T * (K_ * D_) + idx;
  for (int c = 0; c < NCHUNK_T; ++c) {
    const float4 v = *(const float4*)(base + (size_t)c * (K_ * D_));
    s.x += v.x; s.y += v.y; s.z += v.z; s.w += v.w;
  }
  const int k = idx >> 9;
  const float a = s_as[k];
  const float4 cv = *(const float4*)(centers + idx);
  float4 p;
  p.x = s.x - a * cv.x; p.y = s.y - a * cv.y;
  p.z = s.z - a * cv.z; p.w = s.w - a * cv.w;
  *(float4*)(pbuf + (size_t)b * (K_ * D_) + idx) = p;
  float sq = p.x * p.x + p.y * p.y + p.z * p.z + p.w * p.w;
#pragma unroll
  for (int m = 32; m; m >>= 1) sq += __shfl_xor(sq, m);
  if ((tid & 63) == 0) s_sq[tid >> 6] = sq;
  __syncthreads();
  if (tid == 0) sqpart[blockIdx.x] = (s_sq[0] + s_sq[1]) + (s_sq[2] + s_sq[3]);
}

// k2b: normalize (pbuf is L2/L3-hot)
__global__ __launch_bounds__(1024) void k2b(const float* __restrict__ pbuf,
                                            const float* __restrict__ sqpart,
                                            float* __restrict__ out) {
  const int b = blockIdx.x;
  const float tot =
      (sqpart[b * 4] + sqpart[b * 4 + 1]) + (sqpart[b * 4 + 2] + sqpart[b * 4 + 3]);
  const float invn = 1.0f / fmaxf(__builtin_sqrtf(tot), 1e-12f);
  const int idx = threadIdx.x * 4;
  const float4 p = *(const float4*)(pbuf + (size_t)b * (K_ * D_) + idx);
  *(float4*)(out + (size_t)b * (K_ * D_) + idx) =
      (float4){p.x * invn, p.y * invn, p.z * invn, p.w * invn};
}

// legacy single-kernel finalize (smallest-workspace fallback)
template <int NCHUNK_T>
__global__ __launch_bounds__(1024) void k2_old(
    const float* __restrict__ ax_part, const float* __restrict__ asum_part,
    const float* __restrict__ centers, float* __restrict__ out) {
  const int b = blockIdx.x;
  const int tid = threadIdx.x;
  const int wave = tid >> 6;
  const int lane = tid & 63;
  __shared__ float s_asum[K_];
  __shared__ float s_sq[16];
  if (tid < K_) {
    float s = 0.f;
    for (int c = 0; c < NCHUNK_T; ++c) s += asum_part[(b * NCHUNK_T + c) * K_ + tid];
    s_asum[tid] = s;
  }
  __syncthreads();
  const int NPT = (K_ * D_) / 1024;
  float pooled[NPT];
  float sq = 0.f;
  const float* base = ax_part + (size_t)b * NCHUNK_T * (K_ * D_);
#pragma unroll
  for (int i = 0; i < NPT; ++i) {
    const int idx = tid + i * 1024;
    float v = 0.f;
    for (int c = 0; c < NCHUNK_T; ++c) v += base[(size_t)c * (K_ * D_) + idx];
    v -= s_asum[idx >> 9] * centers[idx];
    pooled[i] = v;
    sq = fmaf(v, v, sq);
  }
#pragma unroll
  for (int m = 32; m; m >>= 1) sq += __shfl_xor(sq, m);
  if (lane == 0) s_sq[wave] = sq;
  __syncthreads();
  float tot = 0.f;
#pragma unroll
  for (int wv = 0; wv < 16; ++wv) tot += s_sq[wv];
  const float invn = 1.0f / fmaxf(__builtin_sqrtf(tot), 1e-12f);
#pragma unroll
  for (int i = 0; i < NPT; ++i)
    out[(size_t)b * (K_ * D_) + tid + i * 1024] = pooled[i] * invn;
}

extern "C" void kernel_launch(void* const* d_in, const int* in_sizes, int n_in,
                              void* d_out, int out_size, void* d_ws, size_t ws_size,
                              hipStream_t stream) {
  (void)in_sizes; (void)n_in; (void)out_size;
  const float* x = (const float*)d_in[0];
  const float* centers = (const float*)d_in[1];
  const float* attn_w = (const float*)d_in[2];
  const float* attn_b = (const float*)d_in[3];
  float* out = (float*)d_out;

  const size_t KD = (size_t)K_ * D_;
  const size_t need16 = (size_t)B_ * 16 * KD * 4 + (size_t)B_ * 16 * K_ * 4 +
                        (size_t)B_ * KD * 4 + (size_t)B_ * 4 * 4;
  const size_t need8 = (size_t)B_ * 8 * KD * 4 + (size_t)B_ * 8 * K_ * 4 +
                       (size_t)B_ * KD * 4 + (size_t)B_ * 4 * 4;

  if (ws_size >= need16) {
    float* ax = (float*)d_ws;
    float* as = ax + (size_t)B_ * 16 * KD;
    float* pb = as + (size_t)B_ * 16 * K_;
    float* sp = pb + (size_t)B_ * KD;
    k1_accum<16><<<B_ * 16, THREADS, 0, stream>>>(x, attn_w, attn_b, ax, as);
    k2a<16><<<B_ * 4, 256, 0, stream>>>(ax, as, centers, pb, sp);
    k2b<<<B_, 1024, 0, stream>>>(pb, sp, out);
  } else if (ws_size >= need8) {
    float* ax = (float*)d_ws;
    float* as = ax + (size_t)B_ * 8 * KD;
    float* pb = as + (size_t)B_ * 8 * K_;
    float* sp = pb + (size_t)B_ * KD;
    k1_accum<8><<<B_ * 8, THREADS, 0, stream>>>(x, attn_w, attn_b, ax, as);
    k2a<8><<<B_ * 4, 256, 0, stream>>>(ax, as, centers, pb, sp);
    k2b<<<B_, 1024, 0, stream>>>(pb, sp, out);
  } else {
    float* ax = (float*)d_ws;
    float* as = ax + (size_t)B_ * 8 * KD;
    k1_accum<8><<<B_ * 8, THREADS, 0, stream>>>(x, attn_w, attn_b, ax, as);
    k2_old<8><<<B_, 1024, 0, stream>>>(ax, as, centers, out);
  }
}

// Round 21
// 60.400 us; speedup vs baseline: 1.3351x; 1.0184x over previous
//
#include <hip/hip_runtime.h>

typedef float v2f __attribute__((ext_vector_type(2)));
typedef float v4f __attribute__((ext_vector_type(4)));
typedef __fp16 h2 __attribute__((ext_vector_type(2)));
typedef __fp16 h4 __attribute__((ext_vector_type(4)));

#define B_ 64
#define T_ 2048
#define D_ 512
#define K_ 8
#define THREADS 256
#define TILE_R 32
#define XPITCH 520   // f16 pitch: 512 + 8 pad
#define LGP 9        // logits pitch (f32)
#define APITCH 12    // a-table pitch (f32)
#define LOG2E 1.44269504088896340736f

// Raw barrier discipline (T3/T4): __syncthreads() drains vmcnt(0) before
// s_barrier -- keeps prefetch loads in flight across barriers instead.
#define LGKM0 asm volatile("s_waitcnt lgkmcnt(0)" ::: "memory")
#define BARRIER __builtin_amdgcn_s_barrier()
#define PIN __builtin_amdgcn_sched_barrier(0)

__device__ __forceinline__ float dev_exp2(float v) { return __builtin_amdgcn_exp2f(v); }
__device__ __forceinline__ h2 pack2(float a, float b) { return __builtin_amdgcn_cvt_pkrtz(a, b); }

// Round 21: R20 (WIN, 61.5us) + occupancy trim. wt LDS (8.3KB) was only
// used once in the prologue to build the hoisted B-frags -> load bf[8]
// directly from global (W is 16KB, L2-hot) and delete wt. LDS 48->39.4KB
// -> 4 blocks/CU, matching the 1024-block grid's 4 blocks/CU of work
// (removes the ~33% k1 scheduling tail at 3/CU).
template <int NCHUNK_T>
__global__ __launch_bounds__(THREADS) void k1_accum(
    const float* __restrict__ x, const float* __restrict__ attn_w,
    const float* __restrict__ attn_b, float* __restrict__ ax_part,
    float* __restrict__ asum_part) {
  constexpr int RPC = T_ / NCHUNK_T;
  constexpr int TILES = RPC / TILE_R;  // 4 (NCHUNK=16) or 8 (NCHUNK=8)

  const int blk = blockIdx.x;
  const int b = blk / NCHUNK_T;
  const int chunk = blk % NCHUNK_T;
  const int tid = threadIdx.x;
  const int wave = tid >> 6;
  const int lane = tid & 63;

  __shared__ __align__(16) __fp16 xt[TILE_R * XPITCH];  // 33.3 KB (single buf)
  __shared__ float lg[4 * TILE_R * LGP];                // 4.6 KB (per-wave C partials)
  __shared__ __align__(16) float at[TILE_R * APITCH];   // 1.5 KB
  __shared__ float bt[K_];

  if (tid < K_) bt[tid] = attn_b[tid] * LOG2E;

  // MFMA lane constants (layout verified on-silicon R13/R18/R20):
  //   A[m][k]: m=lane&15, k=(lane>>4)*4+i ; B[k][n]: n=lane&15, same k
  //   C[m][n]: n=lane&15, m=(lane>>4)*4+j
  const int m16 = lane & 15;
  const int kgrp = lane >> 4;
  const int koff = wave * 128 + kgrp * 4;  // wave owns a 128-d K-quarter
  const __fp16* arow0 = xt + m16 * XPITCH + koff;
  const __fp16* arow1 = xt + (16 + m16) * XPITCH + koff;

  const int d0p2 = wave * 128 + lane * 2;  // pass2 d-pair ownership

  v2f acc[K_];
#pragma unroll
  for (int k = 0; k < K_; ++k) acc[k] = (v2f){0.f, 0.f};
  float asum[K_];
#pragma unroll
  for (int k = 0; k < K_; ++k) asum[k] = 0.f;

  const float* xbase = x + ((size_t)b * T_ + (size_t)chunk * RPC) * (size_t)D_;
  const int t4 = tid << 2;

  float4 f0, f1, f2, f3, f4, f5, f6, f7, f8, f9, f10, f11, f12, f13, f14, f15;
#define LOADT(tt)                                                    \
  do {                                                               \
    const float* s_ = xbase + (size_t)(tt) * TILE_R * D_ + t4;       \
    f0 = *(const float4*)(s_ + 0 * 1024);                            \
    f1 = *(const float4*)(s_ + 1 * 1024);                            \
    f2 = *(const float4*)(s_ + 2 * 1024);                            \
    f3 = *(const float4*)(s_ + 3 * 1024);                            \
    f4 = *(const float4*)(s_ + 4 * 1024);                            \
    f5 = *(const float4*)(s_ + 5 * 1024);                            \
    f6 = *(const float4*)(s_ + 6 * 1024);                            \
    f7 = *(const float4*)(s_ + 7 * 1024);                            \
    f8 = *(const float4*)(s_ + 8 * 1024);                            \
    f9 = *(const float4*)(s_ + 9 * 1024);                            \
    f10 = *(const float4*)(s_ + 10 * 1024);                          \
    f11 = *(const float4*)(s_ + 11 * 1024);                          \
    f12 = *(const float4*)(s_ + 12 * 1024);                          \
    f13 = *(const float4*)(s_ + 13 * 1024);                          \
    f14 = *(const float4*)(s_ + 14 * 1024);                          \
    f15 = *(const float4*)(s_ + 15 * 1024);                          \
  } while (0)
#define WRT1(i, F)                                                   \
  do {                                                               \
    const int g_ = (i)*1024 + t4;                                    \
    const h2 lo_ = pack2(F.x, F.y), hi_ = pack2(F.z, F.w);           \
    h4 v_;                                                           \
    v_[0] = lo_[0]; v_[1] = lo_[1]; v_[2] = hi_[0]; v_[3] = hi_[1];  \
    *(h4*)(xt + (g_ >> 9) * XPITCH + (g_ & 511)) = v_;               \
  } while (0)
#define WRITET()                                                     \
  do {                                                               \
    WRT1(0, f0); WRT1(1, f1); WRT1(2, f2); WRT1(3, f3);              \
    WRT1(4, f4); WRT1(5, f5); WRT1(6, f6); WRT1(7, f7);              \
    WRT1(8, f8); WRT1(9, f9); WRT1(10, f10); WRT1(11, f11);          \
    WRT1(12, f12); WRT1(13, f13); WRT1(14, f14); WRT1(15, f15);      \
  } while (0)

  // prologue: stage tile0; B-frags from GLOBAL (W L2-hot, once per block);
  // issue tile1 (stays in flight across barriers, un-drained)
  LOADT(0);
  WRITET();
  h4 bf[8];
  {
    const int wrow = (m16 < K_ ? m16 : (K_ - 1));  // clamp pad cols (C 8..15 unused)
    const float* wg = attn_w + wrow * D_ + koff;
#pragma unroll
    for (int s = 0; s < 8; ++s) {
      const float4 g = *(const float4*)(wg + s * 16);
      const h2 lo = pack2(g.x * LOG2E, g.y * LOG2E);
      const h2 hi = pack2(g.z * LOG2E, g.w * LOG2E);
      bf[s][0] = lo[0]; bf[s][1] = lo[1]; bf[s][2] = hi[0]; bf[s][3] = hi[1];
    }
  }
  LOADT(1);
  PIN;  // pin tile1 issue point
  LGKM0;
  BARRIER;  // xt(0) + bt visible; tile1 (and bf) loads in flight

#pragma unroll
  for (int t = 0; t < TILES; ++t) {
    // ---- pass1: logits = X·W^T via MFMA (A from xt, B from regs)
    {
      v4f c0 = {0.f, 0.f, 0.f, 0.f}, c1 = {0.f, 0.f, 0.f, 0.f};
#pragma unroll
      for (int s = 0; s < 8; ++s) {
        const h4 a0 = *(const h4*)(arow0 + s * 16);
        const h4 a1 = *(const h4*)(arow1 + s * 16);
        c0 = __builtin_amdgcn_mfma_f32_16x16x16f16(a0, bf[s], c0, 0, 0, 0);
        c1 = __builtin_amdgcn_mfma_f32_16x16x16f16(a1, bf[s], c1, 0, 0, 0);
      }
      if (m16 < K_) {
        const int base = (wave * TILE_R + kgrp * 4) * LGP + m16;
#pragma unroll
        for (int j = 0; j < 4; ++j) {
          lg[base + j * LGP] = c0[j];
          lg[base + (16 + j) * LGP] = c1[j];
        }
      }
    }
    LGKM0;
    BARRIER;  // lg visible

    // ---- softmax: lane-per-row (exp2 domain, no max-sub: logits ~N(0,1),
    //      fp32-safe; ratio identical). asum accumulated per owning lane.
    if (wave == 0 && lane < TILE_R) {
      float e[K_];
      float tot = 0.f;
#pragma unroll
      for (int k = 0; k < K_; ++k) {
        const float l = ((lg[(0 * TILE_R + lane) * LGP + k] +
                          lg[(1 * TILE_R + lane) * LGP + k]) +
                         (lg[(2 * TILE_R + lane) * LGP + k] +
                          lg[(3 * TILE_R + lane) * LGP + k])) + bt[k];
        e[k] = dev_exp2(l);
        tot += e[k];
      }
      const float inv = __builtin_amdgcn_rcpf(tot);
      float4* ad = (float4*)(at + lane * APITCH);
      ad[0] = (float4){e[0] * inv, e[1] * inv, e[2] * inv, e[3] * inv};
      ad[1] = (float4){e[4] * inv, e[5] * inv, e[6] * inv, e[7] * inv};
#pragma unroll
      for (int k = 0; k < K_; ++k) asum[k] += e[k] * inv;
    }
    LGKM0;
    BARRIER;  // at visible

    // ---- pass2: acc[k] += a[r][k] * x[r][d-pair]; a broadcast, x b32
#pragma unroll 4
    for (int rr = 0; rr < TILE_R; ++rr) {
      const float4 alo = *(const float4*)(at + rr * APITCH);
      const float4 ahi = *(const float4*)(at + rr * APITCH + 4);
      const h2 xp = *(const h2*)(xt + rr * XPITCH + d0p2);
      const v2f xv = {(float)xp[0], (float)xp[1]};
      acc[0] += (v2f){alo.x, alo.x} * xv;
      acc[1] += (v2f){alo.y, alo.y} * xv;
      acc[2] += (v2f){alo.z, alo.z} * xv;
      acc[3] += (v2f){alo.w, alo.w} * xv;
      acc[4] += (v2f){ahi.x, ahi.x} * xv;
      acc[5] += (v2f){ahi.y, ahi.y} * xv;
      acc[6] += (v2f){ahi.z, ahi.z} * xv;
      acc[7] += (v2f){ahi.w, ahi.w} * xv;
    }
    LGKM0;
    BARRIER;  // all waves done reading xt(t)

    // ---- drain tile t+1 into xt (loads issued a full iter ago: covered);
    //      issue tile t+2 (covered by next iter's pass1..pass2)
    if (t + 1 < TILES) {
      WRITET();
      if (t + 2 < TILES) {
        LOADT(t + 2);
        PIN;
      }
      LGKM0;
      BARRIER;  // xt(t+1) visible
    }
  }
#undef LOADT
#undef WRT1
#undef WRITET

  // ---- write per-chunk partials
  float* outp = ax_part + (size_t)blk * (K_ * D_);
#pragma unroll
  for (int k = 0; k < K_; ++k) *(v2f*)(outp + k * D_ + d0p2) = acc[k];
  // asum: reduce across the 32 row-owning lanes of wave 0
  if (wave == 0 && lane < TILE_R) {
#pragma unroll
    for (int k = 0; k < K_; ++k) {
      float v = asum[k];
      v += __shfl_xor(v, 1);
      v += __shfl_xor(v, 2);
      v += __shfl_xor(v, 4);
      v += __shfl_xor(v, 8);
      v += __shfl_xor(v, 16);
      asum[k] = v;
    }
    if (lane == 0) {
      float* ap = asum_part + blk * K_;
#pragma unroll
      for (int k = 0; k < K_; ++k) ap[k] = asum[k];
    }
  }
}

// k2a: 4 blocks per batch -> reduce chunks, subtract asum*centers, partial sq
template <int NCHUNK_T>
__global__ __launch_bounds__(256) void k2a(
    const float* __restrict__ ax_part, const float* __restrict__ asum_part,
    const float* __restrict__ centers, float* __restrict__ pbuf,
    float* __restrict__ sqpart) {
  const int b = blockIdx.x >> 2;
  const int q = blockIdx.x & 3;
  const int tid = threadIdx.x;
  __shared__ float s_as[K_];
  __shared__ float s_sq[4];
  if (tid < K_) {
    float s = 0.f;
    for (int c = 0; c < NCHUNK_T; ++c) s += asum_part[(b * NCHUNK_T + c) * K_ + tid];
    s_as[tid] = s;
  }
  __syncthreads();
  const int idx = q * 1024 + tid * 4;
  float4 s = {0.f, 0.f, 0.f, 0.f};
  const float* base = ax_part + (size_t)b * NCHUNK_T * (K_ * D_) + idx;
  for (int c = 0; c < NCHUNK_T; ++c) {
    const float4 v = *(const float4*)(base + (size_t)c * (K_ * D_));
    s.x += v.x; s.y += v.y; s.z += v.z; s.w += v.w;
  }
  const int k = idx >> 9;
  const float a = s_as[k];
  const float4 cv = *(const float4*)(centers + idx);
  float4 p;
  p.x = s.x - a * cv.x; p.y = s.y - a * cv.y;
  p.z = s.z - a * cv.z; p.w = s.w - a * cv.w;
  *(float4*)(pbuf + (size_t)b * (K_ * D_) + idx) = p;
  float sq = p.x * p.x + p.y * p.y + p.z * p.z + p.w * p.w;
#pragma unroll
  for (int m = 32; m; m >>= 1) sq += __shfl_xor(sq, m);
  if ((tid & 63) == 0) s_sq[tid >> 6] = sq;
  __syncthreads();
  if (tid == 0) sqpart[blockIdx.x] = (s_sq[0] + s_sq[1]) + (s_sq[2] + s_sq[3]);
}

// k2b: normalize (pbuf is L2/L3-hot)
__global__ __launch_bounds__(1024) void k2b(const float* __restrict__ pbuf,
                                            const float* __restrict__ sqpart,
                                            float* __restrict__ out) {
  const int b = blockIdx.x;
  const float tot =
      (sqpart[b * 4] + sqpart[b * 4 + 1]) + (sqpart[b * 4 + 2] + sqpart[b * 4 + 3]);
  const float invn = 1.0f / fmaxf(__builtin_sqrtf(tot), 1e-12f);
  const int idx = threadIdx.x * 4;
  const float4 p = *(const float4*)(pbuf + (size_t)b * (K_ * D_) + idx);
  *(float4*)(out + (size_t)b * (K_ * D_) + idx) =
      (float4){p.x * invn, p.y * invn, p.z * invn, p.w * invn};
}

// legacy single-kernel finalize (smallest-workspace fallback)
template <int NCHUNK_T>
__global__ __launch_bounds__(1024) void k2_old(
    const float* __restrict__ ax_part, const float* __restrict__ asum_part,
    const float* __restrict__ centers, float* __restrict__ out) {
  const int b = blockIdx.x;
  const int tid = threadIdx.x;
  const int wave = tid >> 6;
  const int lane = tid & 63;
  __shared__ float s_asum[K_];
  __shared__ float s_sq[16];
  if (tid < K_) {
    float s = 0.f;
    for (int c = 0; c < NCHUNK_T; ++c) s += asum_part[(b * NCHUNK_T + c) * K_ + tid];
    s_asum[tid] = s;
  }
  __syncthreads();
  const int NPT = (K_ * D_) / 1024;
  float pooled[NPT];
  float sq = 0.f;
  const float* base = ax_part + (size_t)b * NCHUNK_T * (K_ * D_);
#pragma unroll
  for (int i = 0; i < NPT; ++i) {
    const int idx = tid + i * 1024;
    float v = 0.f;
    for (int c = 0; c < NCHUNK_T; ++c) v += base[(size_t)c * (K_ * D_) + idx];
    v -= s_asum[idx >> 9] * centers[idx];
    pooled[i] = v;
    sq = fmaf(v, v, sq);
  }
#pragma unroll
  for (int m = 32; m; m >>= 1) sq += __shfl_xor(sq, m);
  if (lane == 0) s_sq[wave] = sq;
  __syncthreads();
  float tot = 0.f;
#pragma unroll
  for (int wv = 0; wv < 16; ++wv) tot += s_sq[wv];
  const float invn = 1.0f / fmaxf(__builtin_sqrtf(tot), 1e-12f);
#pragma unroll
  for (int i = 0; i < NPT; ++i)
    out[(size_t)b * (K_ * D_) + tid + i * 1024] = pooled[i] * invn;
}

extern "C" void kernel_launch(void* const* d_in, const int* in_sizes, int n_in,
                              void* d_out, int out_size, void* d_ws, size_t ws_size,
                              hipStream_t stream) {
  (void)in_sizes; (void)n_in; (void)out_size;
  const float* x = (const float*)d_in[0];
  const float* centers = (const float*)d_in[1];
  const float* attn_w = (const float*)d_in[2];
  const float* attn_b = (const float*)d_in[3];
  float* out = (float*)d_out;

  const size_t KD = (size_t)K_ * D_;
  const size_t need16 = (size_t)B_ * 16 * KD * 4 + (size_t)B_ * 16 * K_ * 4 +
                        (size_t)B_ * KD * 4 + (size_t)B_ * 4 * 4;
  const size_t need8 = (size_t)B_ * 8 * KD * 4 + (size_t)B_ * 8 * K_ * 4 +
                       (size_t)B_ * KD * 4 + (size_t)B_ * 4 * 4;

  if (ws_size >= need16) {
    float* ax = (float*)d_ws;
    float* as = ax + (size_t)B_ * 16 * KD;
    float* pb = as + (size_t)B_ * 16 * K_;
    float* sp = pb + (size_t)B_ * KD;
    k1_accum<16><<<B_ * 16, THREADS, 0, stream>>>(x, attn_w, attn_b, ax, as);
    k2a<16><<<B_ * 4, 256, 0, stream>>>(ax, as, centers, pb, sp);
    k2b<<<B_, 1024, 0, stream>>>(pb, sp, out);
  } else if (ws_size >= need8) {
    float* ax = (float*)d_ws;
    float* as = ax + (size_t)B_ * 8 * KD;
    float* pb = as + (size_t)B_ * 8 * K_;
    float* sp = pb + (size_t)B_ * KD;
    k1_accum<8><<<B_ * 8, THREADS, 0, stream>>>(x, attn_w, attn_b, ax, as);
    k2a<8><<<B_ * 4, 256, 0, stream>>>(ax, as, centers, pb, sp);
    k2b<<<B_, 1024, 0, stream>>>(pb, sp, out);
  } else {
    float* ax = (float*)d_ws;
    float* as = ax + (size_t)B_ * 8 * KD;
    k1_accum<8><<<B_ * 8, THREADS, 0, stream>>>(x, attn_w, attn_b, ax, as);
    k2_old<8><<<B_, 1024, 0, stream>>>(ax, as, centers, out);
  }
}

// Round 22
// 55.705 us; speedup vs baseline: 1.4476x; 1.0843x over previous
//
#include <hip/hip_runtime.h>

typedef float v2f __attribute__((ext_vector_type(2)));
typedef float v4f __attribute__((ext_vector_type(4)));
typedef __fp16 h2 __attribute__((ext_vector_type(2)));
typedef __fp16 h4 __attribute__((ext_vector_type(4)));

#define B_ 64
#define T_ 2048
#define D_ 512
#define K_ 8
#define THREADS 256
#define TILE_R 32
#define XPITCH 520   // f16 pitch: 512 + 8 pad
#define LGP 9        // logits pitch (f32)
#define APITCH 12    // a-table pitch (f32)
#define LOG2E 1.44269504088896340736f

// Raw barrier discipline (T3/T4): __syncthreads() drains vmcnt(0) before
// s_barrier -- keeps prefetch loads in flight across barriers instead.
#define LGKM0 asm volatile("s_waitcnt lgkmcnt(0)" ::: "memory")
#define BARRIER __builtin_amdgcn_s_barrier()
#define PIN __builtin_amdgcn_sched_barrier(0)

__device__ __forceinline__ float dev_exp2(float v) { return __builtin_amdgcn_exp2f(v); }
__device__ __forceinline__ h2 pack2(float a, float b) { return __builtin_amdgcn_cvt_pkrtz(a, b); }

// Round 22: R21 (60.4us) with NCHUNK 16->8. (1) ax_part halves: -8.4MB k1
// write, -8.4MB k2a read (~2.5us traffic); (2) TILES 4->8 amortizes the
// serial prologue/epilogue over 2x work; 512 blocks = exactly 2/CU, no
// scheduling tail. Pipeline (counted vmcnt, raw barriers) is the latency
// cover, so the TLP reduction should be tolerable.
template <int NCHUNK_T>
__global__ __launch_bounds__(THREADS) void k1_accum(
    const float* __restrict__ x, const float* __restrict__ attn_w,
    const float* __restrict__ attn_b, float* __restrict__ ax_part,
    float* __restrict__ asum_part) {
  constexpr int RPC = T_ / NCHUNK_T;
  constexpr int TILES = RPC / TILE_R;  // 8 (NCHUNK=8) or 4 (NCHUNK=16)

  const int blk = blockIdx.x;
  const int b = blk / NCHUNK_T;
  const int chunk = blk % NCHUNK_T;
  const int tid = threadIdx.x;
  const int wave = tid >> 6;
  const int lane = tid & 63;

  __shared__ __align__(16) __fp16 xt[TILE_R * XPITCH];  // 33.3 KB (single buf)
  __shared__ float lg[4 * TILE_R * LGP];                // 4.6 KB
  __shared__ __align__(16) float at[TILE_R * APITCH];   // 1.5 KB
  __shared__ float bt[K_];

  if (tid < K_) bt[tid] = attn_b[tid] * LOG2E;

  // MFMA lane constants (layout verified on-silicon R13/R18/R20):
  //   A[m][k]: m=lane&15, k=(lane>>4)*4+i ; B[k][n]: n=lane&15, same k
  //   C[m][n]: n=lane&15, m=(lane>>4)*4+j
  const int m16 = lane & 15;
  const int kgrp = lane >> 4;
  const int koff = wave * 128 + kgrp * 4;  // wave owns a 128-d K-quarter
  const __fp16* arow0 = xt + m16 * XPITCH + koff;
  const __fp16* arow1 = xt + (16 + m16) * XPITCH + koff;

  const int d0p2 = wave * 128 + lane * 2;  // pass2 d-pair ownership

  v2f acc[K_];
#pragma unroll
  for (int k = 0; k < K_; ++k) acc[k] = (v2f){0.f, 0.f};
  float asum[K_];
#pragma unroll
  for (int k = 0; k < K_; ++k) asum[k] = 0.f;

  const float* xbase = x + ((size_t)b * T_ + (size_t)chunk * RPC) * (size_t)D_;
  const int t4 = tid << 2;

  float4 f0, f1, f2, f3, f4, f5, f6, f7, f8, f9, f10, f11, f12, f13, f14, f15;
#define LOADT(tt)                                                    \
  do {                                                               \
    const float* s_ = xbase + (size_t)(tt) * TILE_R * D_ + t4;       \
    f0 = *(const float4*)(s_ + 0 * 1024);                            \
    f1 = *(const float4*)(s_ + 1 * 1024);                            \
    f2 = *(const float4*)(s_ + 2 * 1024);                            \
    f3 = *(const float4*)(s_ + 3 * 1024);                            \
    f4 = *(const float4*)(s_ + 4 * 1024);                            \
    f5 = *(const float4*)(s_ + 5 * 1024);                            \
    f6 = *(const float4*)(s_ + 6 * 1024);                            \
    f7 = *(const float4*)(s_ + 7 * 1024);                            \
    f8 = *(const float4*)(s_ + 8 * 1024);                            \
    f9 = *(const float4*)(s_ + 9 * 1024);                            \
    f10 = *(const float4*)(s_ + 10 * 1024);                          \
    f11 = *(const float4*)(s_ + 11 * 1024);                          \
    f12 = *(const float4*)(s_ + 12 * 1024);                          \
    f13 = *(const float4*)(s_ + 13 * 1024);                          \
    f14 = *(const float4*)(s_ + 14 * 1024);                          \
    f15 = *(const float4*)(s_ + 15 * 1024);                          \
  } while (0)
#define WRT1(i, F)                                                   \
  do {                                                               \
    const int g_ = (i)*1024 + t4;                                    \
    const h2 lo_ = pack2(F.x, F.y), hi_ = pack2(F.z, F.w);           \
    h4 v_;                                                           \
    v_[0] = lo_[0]; v_[1] = lo_[1]; v_[2] = hi_[0]; v_[3] = hi_[1];  \
    *(h4*)(xt + (g_ >> 9) * XPITCH + (g_ & 511)) = v_;               \
  } while (0)
#define WRITET()                                                     \
  do {                                                               \
    WRT1(0, f0); WRT1(1, f1); WRT1(2, f2); WRT1(3, f3);              \
    WRT1(4, f4); WRT1(5, f5); WRT1(6, f6); WRT1(7, f7);              \
    WRT1(8, f8); WRT1(9, f9); WRT1(10, f10); WRT1(11, f11);          \
    WRT1(12, f12); WRT1(13, f13); WRT1(14, f14); WRT1(15, f15);      \
  } while (0)

  // prologue: stage tile0; B-frags from GLOBAL (W L2-hot, once per block);
  // issue tile1 (stays in flight across barriers, un-drained)
  LOADT(0);
  WRITET();
  h4 bf[8];
  {
    const int wrow = (m16 < K_ ? m16 : (K_ - 1));  // clamp pad cols
    const float* wg = attn_w + wrow * D_ + koff;
#pragma unroll
    for (int s = 0; s < 8; ++s) {
      const float4 g = *(const float4*)(wg + s * 16);
      const h2 lo = pack2(g.x * LOG2E, g.y * LOG2E);
      const h2 hi = pack2(g.z * LOG2E, g.w * LOG2E);
      bf[s][0] = lo[0]; bf[s][1] = lo[1]; bf[s][2] = hi[0]; bf[s][3] = hi[1];
    }
  }
  LOADT(1);
  PIN;  // pin tile1 issue point
  LGKM0;
  BARRIER;  // xt(0) + bt visible; tile1 loads in flight

#pragma unroll
  for (int t = 0; t < TILES; ++t) {
    // ---- pass1: logits = X·W^T via MFMA (A from xt, B from regs)
    {
      v4f c0 = {0.f, 0.f, 0.f, 0.f}, c1 = {0.f, 0.f, 0.f, 0.f};
#pragma unroll
      for (int s = 0; s < 8; ++s) {
        const h4 a0 = *(const h4*)(arow0 + s * 16);
        const h4 a1 = *(const h4*)(arow1 + s * 16);
        c0 = __builtin_amdgcn_mfma_f32_16x16x16f16(a0, bf[s], c0, 0, 0, 0);
        c1 = __builtin_amdgcn_mfma_f32_16x16x16f16(a1, bf[s], c1, 0, 0, 0);
      }
      if (m16 < K_) {
        const int base = (wave * TILE_R + kgrp * 4) * LGP + m16;
#pragma unroll
        for (int j = 0; j < 4; ++j) {
          lg[base + j * LGP] = c0[j];
          lg[base + (16 + j) * LGP] = c1[j];
        }
      }
    }
    LGKM0;
    BARRIER;  // lg visible

    // ---- softmax: lane-per-row (exp2 domain, no max-sub: logits ~N(0,1),
    //      fp32-safe; ratio identical). asum accumulated per owning lane.
    if (wave == 0 && lane < TILE_R) {
      float e[K_];
      float tot = 0.f;
#pragma unroll
      for (int k = 0; k < K_; ++k) {
        const float l = ((lg[(0 * TILE_R + lane) * LGP + k] +
                          lg[(1 * TILE_R + lane) * LGP + k]) +
                         (lg[(2 * TILE_R + lane) * LGP + k] +
                          lg[(3 * TILE_R + lane) * LGP + k])) + bt[k];
        e[k] = dev_exp2(l);
        tot += e[k];
      }
      const float inv = __builtin_amdgcn_rcpf(tot);
      float4* ad = (float4*)(at + lane * APITCH);
      ad[0] = (float4){e[0] * inv, e[1] * inv, e[2] * inv, e[3] * inv};
      ad[1] = (float4){e[4] * inv, e[5] * inv, e[6] * inv, e[7] * inv};
#pragma unroll
      for (int k = 0; k < K_; ++k) asum[k] += e[k] * inv;
    }
    LGKM0;
    BARRIER;  // at visible

    // ---- pass2: acc[k] += a[r][k] * x[r][d-pair]; a broadcast, x b32
#pragma unroll 4
    for (int rr = 0; rr < TILE_R; ++rr) {
      const float4 alo = *(const float4*)(at + rr * APITCH);
      const float4 ahi = *(const float4*)(at + rr * APITCH + 4);
      const h2 xp = *(const h2*)(xt + rr * XPITCH + d0p2);
      const v2f xv = {(float)xp[0], (float)xp[1]};
      acc[0] += (v2f){alo.x, alo.x} * xv;
      acc[1] += (v2f){alo.y, alo.y} * xv;
      acc[2] += (v2f){alo.z, alo.z} * xv;
      acc[3] += (v2f){alo.w, alo.w} * xv;
      acc[4] += (v2f){ahi.x, ahi.x} * xv;
      acc[5] += (v2f){ahi.y, ahi.y} * xv;
      acc[6] += (v2f){ahi.z, ahi.z} * xv;
      acc[7] += (v2f){ahi.w, ahi.w} * xv;
    }
    LGKM0;
    BARRIER;  // all waves done reading xt(t)

    // ---- drain tile t+1 into xt (loads issued a full iter ago: covered);
    //      issue tile t+2 (covered by next iter's pass1..pass2)
    if (t + 1 < TILES) {
      WRITET();
      if (t + 2 < TILES) {
        LOADT(t + 2);
        PIN;
      }
      LGKM0;
      BARRIER;  // xt(t+1) visible
    }
  }
#undef LOADT
#undef WRT1
#undef WRITET

  // ---- write per-chunk partials
  float* outp = ax_part + (size_t)blk * (K_ * D_);
#pragma unroll
  for (int k = 0; k < K_; ++k) *(v2f*)(outp + k * D_ + d0p2) = acc[k];
  // asum: reduce across the 32 row-owning lanes of wave 0
  if (wave == 0 && lane < TILE_R) {
#pragma unroll
    for (int k = 0; k < K_; ++k) {
      float v = asum[k];
      v += __shfl_xor(v, 1);
      v += __shfl_xor(v, 2);
      v += __shfl_xor(v, 4);
      v += __shfl_xor(v, 8);
      v += __shfl_xor(v, 16);
      asum[k] = v;
    }
    if (lane == 0) {
      float* ap = asum_part + blk * K_;
#pragma unroll
      for (int k = 0; k < K_; ++k) ap[k] = asum[k];
    }
  }
}

// k2a: 4 blocks per batch -> reduce chunks, subtract asum*centers, partial sq
template <int NCHUNK_T>
__global__ __launch_bounds__(256) void k2a(
    const float* __restrict__ ax_part, const float* __restrict__ asum_part,
    const float* __restrict__ centers, float* __restrict__ pbuf,
    float* __restrict__ sqpart) {
  const int b = blockIdx.x >> 2;
  const int q = blockIdx.x & 3;
  const int tid = threadIdx.x;
  __shared__ float s_as[K_];
  __shared__ float s_sq[4];
  if (tid < K_) {
    float s = 0.f;
    for (int c = 0; c < NCHUNK_T; ++c) s += asum_part[(b * NCHUNK_T + c) * K_ + tid];
    s_as[tid] = s;
  }
  __syncthreads();
  const int idx = q * 1024 + tid * 4;
  float4 s = {0.f, 0.f, 0.f, 0.f};
  const float* base = ax_part + (size_t)b * NCHUNK_T * (K_ * D_) + idx;
  for (int c = 0; c < NCHUNK_T; ++c) {
    const float4 v = *(const float4*)(base + (size_t)c * (K_ * D_));
    s.x += v.x; s.y += v.y; s.z += v.z; s.w += v.w;
  }
  const int k = idx >> 9;
  const float a = s_as[k];
  const float4 cv = *(const float4*)(centers + idx);
  float4 p;
  p.x = s.x - a * cv.x; p.y = s.y - a * cv.y;
  p.z = s.z - a * cv.z; p.w = s.w - a * cv.w;
  *(float4*)(pbuf + (size_t)b * (K_ * D_) + idx) = p;
  float sq = p.x * p.x + p.y * p.y + p.z * p.z + p.w * p.w;
#pragma unroll
  for (int m = 32; m; m >>= 1) sq += __shfl_xor(sq, m);
  if ((tid & 63) == 0) s_sq[tid >> 6] = sq;
  __syncthreads();
  if (tid == 0) sqpart[blockIdx.x] = (s_sq[0] + s_sq[1]) + (s_sq[2] + s_sq[3]);
}

// k2b: normalize (pbuf is L2/L3-hot, 1MB)
__global__ __launch_bounds__(1024) void k2b(const float* __restrict__ pbuf,
                                            const float* __restrict__ sqpart,
                                            float* __restrict__ out) {
  const int b = blockIdx.x;
  const float tot =
      (sqpart[b * 4] + sqpart[b * 4 + 1]) + (sqpart[b * 4 + 2] + sqpart[b * 4 + 3]);
  const float invn = 1.0f / fmaxf(__builtin_sqrtf(tot), 1e-12f);
  const int idx = threadIdx.x * 4;
  const float4 p = *(const float4*)(pbuf + (size_t)b * (K_ * D_) + idx);
  *(float4*)(out + (size_t)b * (K_ * D_) + idx) =
      (float4){p.x * invn, p.y * invn, p.z * invn, p.w * invn};
}

// legacy single-kernel finalize (smallest-workspace fallback)
template <int NCHUNK_T>
__global__ __launch_bounds__(1024) void k2_old(
    const float* __restrict__ ax_part, const float* __restrict__ asum_part,
    const float* __restrict__ centers, float* __restrict__ out) {
  const int b = blockIdx.x;
  const int tid = threadIdx.x;
  const int wave = tid >> 6;
  const int lane = tid & 63;
  __shared__ float s_asum[K_];
  __shared__ float s_sq[16];
  if (tid < K_) {
    float s = 0.f;
    for (int c = 0; c < NCHUNK_T; ++c) s += asum_part[(b * NCHUNK_T + c) * K_ + tid];
    s_asum[tid] = s;
  }
  __syncthreads();
  const int NPT = (K_ * D_) / 1024;
  float pooled[NPT];
  float sq = 0.f;
  const float* base = ax_part + (size_t)b * NCHUNK_T * (K_ * D_);
#pragma unroll
  for (int i = 0; i < NPT; ++i) {
    const int idx = tid + i * 1024;
    float v = 0.f;
    for (int c = 0; c < NCHUNK_T; ++c) v += base[(size_t)c * (K_ * D_) + idx];
    v -= s_asum[idx >> 9] * centers[idx];
    pooled[i] = v;
    sq = fmaf(v, v, sq);
  }
#pragma unroll
  for (int m = 32; m; m >>= 1) sq += __shfl_xor(sq, m);
  if (lane == 0) s_sq[wave] = sq;
  __syncthreads();
  float tot = 0.f;
#pragma unroll
  for (int wv = 0; wv < 16; ++wv) tot += s_sq[wv];
  const float invn = 1.0f / fmaxf(__builtin_sqrtf(tot), 1e-12f);
#pragma unroll
  for (int i = 0; i < NPT; ++i)
    out[(size_t)b * (K_ * D_) + tid + i * 1024] = pooled[i] * invn;
}

extern "C" void kernel_launch(void* const* d_in, const int* in_sizes, int n_in,
                              void* d_out, int out_size, void* d_ws, size_t ws_size,
                              hipStream_t stream) {
  (void)in_sizes; (void)n_in; (void)out_size;
  const float* x = (const float*)d_in[0];
  const float* centers = (const float*)d_in[1];
  const float* attn_w = (const float*)d_in[2];
  const float* attn_b = (const float*)d_in[3];
  float* out = (float*)d_out;

  const size_t KD = (size_t)K_ * D_;
  const size_t need8 = (size_t)B_ * 8 * KD * 4 + (size_t)B_ * 8 * K_ * 4 +
                       (size_t)B_ * KD * 4 + (size_t)B_ * 4 * 4;

  if (ws_size >= need8) {
    float* ax = (float*)d_ws;
    float* as = ax + (size_t)B_ * 8 * KD;
    float* pb = as + (size_t)B_ * 8 * K_;
    float* sp = pb + (size_t)B_ * KD;
    k1_accum<8><<<B_ * 8, THREADS, 0, stream>>>(x, attn_w, attn_b, ax, as);
    k2a<8><<<B_ * 4, 256, 0, stream>>>(ax, as, centers, pb, sp);
    k2b<<<B_, 1024, 0, stream>>>(pb, sp, out);
  } else {
    float* ax = (float*)d_ws;
    float* as = ax + (size_t)B_ * 8 * KD;
    k1_accum<8><<<B_ * 8, THREADS, 0, stream>>>(x, attn_w, attn_b, ax, as);
    k2_old<8><<<B_, 1024, 0, stream>>>(ax, as, centers, out);
  }
}